// Round 12
// baseline (174.351 us; speedup 1.0000x reference)
//
#include <hip/hip_runtime.h>
#include <hip/hip_bf16.h>
#include <cstdint>

typedef unsigned short u16;
typedef unsigned int u32;
typedef unsigned long long u64;
typedef __bf16 bf16x8 __attribute__((ext_vector_type(8)));
typedef float f32x4 __attribute__((ext_vector_type(4)));
typedef u16 u16x8 __attribute__((ext_vector_type(8)));

#define FPSCALE 1048576.0f          // 2^20 fixed-point for BN stats
#define FPINV   (1.0f / 1048576.0f)
#define NSLICE 16                   // atomic-contention slices

// ---------- helpers ----------
__device__ __forceinline__ u16 f2b(float f) {          // fp32 -> bf16 RNE
    unsigned int u = __float_as_uint(f);
    u += 0x7fffu + ((u >> 16) & 1u);
    return (u16)(u >> 16);
}
__device__ __forceinline__ float b2f(u16 h) {
    return __uint_as_float(((unsigned int)h) << 16);
}
__device__ __forceinline__ void async_cp16(void* lds, const void* g) {
    __builtin_amdgcn_global_load_lds((const __attribute__((address_space(1))) void*)g,
                                     (__attribute__((address_space(3))) void*)lds, 16, 0, 0);
}
__device__ __forceinline__ u64 ld_agent_u64(const u64* p) {
    return __hip_atomic_load(p, __ATOMIC_RELAXED, __HIP_MEMORY_SCOPE_AGENT);
}
// monotone unsigned mapping of float bits (order-preserving, EXACT)
__device__ __forceinline__ u32 fmono(float f) {
    u32 u = __float_as_uint(f);
    return u ^ (((u32)((int)u >> 31)) | 0x80000000u);
}
__device__ __forceinline__ u64 shfl_xor_u64(u64 v, int mask) {
    u32 lo = (u32)v, hi = (u32)(v >> 32);
    lo = (u32)__shfl_xor((int)lo, mask);
    hi = (u32)__shfl_xor((int)hi, mask);
    return ((u64)hi << 32) | lo;
}
// insert exact key into descending top-3 (keys unique: idx field breaks ties)
__device__ __forceinline__ void ins3(u64 k, u64& k0, u64& k1, u64& k2) {
    bool c0 = k > k0, c1 = k > k1, c2 = k > k2;
    k2 = c1 ? k1 : (c2 ? k : k2);
    k1 = c0 ? k0 : (c1 ? k : k1);
    k0 = c0 ? k : k0;
}

// ================= prep kernel: cvt + feature2 transpose + stat-zero =================
// R12: feature1 transpose (NB_T1) removed -- mlp loads its own feature1 slab directly.
#define NB_CVT 160
#define NB_T2  512

__global__ __launch_bounds__(256, 8) void prep_kernel(const float* __restrict__ w1,
                                                      const float* __restrict__ w2,
                                                      u16* __restrict__ wb,
                                                      const float* __restrict__ feature2,
                                                      u16* __restrict__ f2t,
                                                      u64* __restrict__ SZ) {
    __shared__ __align__(16) float t[64][65];
    int ci = blockIdx.x;
    int tid = threadIdx.x;

    if (ci >= NB_CVT + NB_T2) {
        // ---- zero stats: S1[16][512] | S2[16][512] | BAR (per graph replay) ----
        for (int i = tid; i < 2 * NSLICE * 512; i += 256) SZ[i] = 0;
        if (tid == 0) *(int*)(SZ + 2 * NSLICE * 512) = 0;
        return;
    }
    if (ci < NB_CVT) {
        int i = ci * 256 + tid;
        if (i < 40960) {
            const float* src = (i < 24576) ? w1 : w2;
            int k = (i < 24576) ? i : (i - 24576);
            float4 v = *(const float4*)&src[(size_t)k * 4];
            ushort4 o;
            o.x = f2b(v.x); o.y = f2b(v.y); o.z = f2b(v.z); o.w = f2b(v.w);
            *(ushort4*)&wb[(size_t)i * 4] = o;
        }
        return;
    }
    // ---- transpose feature2 [B][256][2048] -> F2T [B][2048][256] bf16 ----
    int lin = ci - NB_CVT;
    int s0 = (lin & 31) * 64, c0 = ((lin >> 5) & 3) * 64, b = lin >> 7;
    const float* ib = feature2 + (size_t)b * 256 * 2048;
    u16* ob = f2t + (size_t)b * 2048 * 256;
    int col = tid & 63, r0 = tid >> 6;
#pragma unroll
    for (int p = 0; p < 16; ++p) {
        int c = p * 4 + r0;
        t[c][col] = ib[(size_t)(c0 + c) * 2048 + s0 + col];
    }
    __syncthreads();
#pragma unroll
    for (int p = 0; p < 16; ++p) {
        int s = p * 4 + r0;
        ob[(size_t)(s0 + s) * 256 + c0 + col] = f2b(t[col][s]);
    }
}

// ================= mlp_fused: NN -> gather+GEMM1 -> BN1 -> GEMM2 -> BN2 -> out =================
// R12 layout (160 KB LDS, 1 block/CU):
//   0      ..32768  : AS dbuf 2x[128][64] bf16    (phase A)   / A2 [128][256] (phase B)
//   32768  ..98304  : BS dbuf 2x[256][64] bf16    (phase A)   / A2 cont.+BS2 b0 (phase B)
//   65536  ..131072 : BS2 dbuf (phase B)
//   98304  ..131072 : F1a = feature1 slab rows c=0..64   f32 [64][128]
//   131072 ..163840 : pk 2048xfloat4 (NN)  ->  F1b rows c=64..128 (after NN)
//   131072 ..141312 : SC/SC2/BNT stats (epilogues; pk/F1b dead by then)
// W1 tiles 0+1 and F1a are prefetched BEFORE the NN scan (latency hidden under 12us
// of NN VALU). Gather setup is per-wave via shfl (wave's 16 NN queries == its own
// gather rows) -- no IDXL LDS, no extra barrier. pk unpadded; bank aliasing across
// the 4 ck-groups is broken by traversal rotation (it + 2*ck) & 63 (order-independent).
__device__ __forceinline__ void gridbar(int* cnt, int target) {
    __syncthreads();                 // drain this block's stat atomics (vmcnt 0)
    if (threadIdx.x == 0) {
        __hip_atomic_fetch_add(cnt, 1, __ATOMIC_RELAXED, __HIP_MEMORY_SCOPE_AGENT);
        while (__hip_atomic_load(cnt, __ATOMIC_RELAXED, __HIP_MEMORY_SCOPE_AGENT) < target)
            __builtin_amdgcn_s_sleep(16);
        __atomic_signal_fence(__ATOMIC_SEQ_CST);   // compiler barrier only
    }
    __syncthreads();
}

__global__ __launch_bounds__(512, 1) void mlp_fused(const float* __restrict__ pos1,
                                                    const float* __restrict__ pos2,
                                                    const u16* __restrict__ F2T,
                                                    const float* __restrict__ feature1,
                                                    const u16* __restrict__ W1b,
                                                    const float* __restrict__ b1,
                                                    const u16* __restrict__ W2b,
                                                    const float* __restrict__ b2,
                                                    u64* __restrict__ S1,
                                                    const float* __restrict__ g1,
                                                    const float* __restrict__ be1,
                                                    u64* __restrict__ S2,
                                                    const float* __restrict__ g2,
                                                    const float* __restrict__ be2,
                                                    float* __restrict__ OUT,
                                                    int* __restrict__ BAR) {
    __shared__ __align__(16) char smem[163840];
    u16* AS  = (u16*)smem;                     // phase A: A dbuf 2x[128][64] (32 KB)
    u16* BS  = (u16*)(smem + 32768);           // phase A: B dbuf 2x[256][64] (64 KB)
    u16* A2  = (u16*)smem;                     // phase B: A tile [128][256]  (64 KB, overlay)
    u16* BS2 = (u16*)(smem + 65536);           // phase B: B dbuf 2x[256][64] (64 KB)
    float* F1a = (float*)(smem + 98304);       // [64][128] f32 rows c=0..64   (32 KB)
    float* F1b = (float*)(smem + 131072);      // [64][128] f32 rows c=64..128 (32 KB, after NN)
    float4* pk = (float4*)(smem + 131072);     // 2048 float4 (NN phase, 32 KB)
    float* SC  = (float*)(smem + 131072);      // stats scratch [4][256] (4 KB)
    float* SC2 = (float*)(smem + 135168);      // 4 KB
    float2* BNT = (float2*)(smem + 139264);    // 2 KB fold table

    int tid = threadIdx.x, bid = blockIdx.x;
    int lane = tid & 63, wv = tid >> 6;        // 8 waves
    int l15 = lane & 15, q = lane >> 4;
    int lrow = lane >> 3, lchunk = lane & 7, schunk = lchunk ^ lrow;
    int j0 = bid * 128;
    int rw = wv & 3;                           // row-group (4)
    int cg = wv >> 2;                          // col-group (2)
    int wrow = rw * 32;
    int cbase = cg * 128;
    int sl = (bid & (NSLICE - 1)) * 512;
    int bb = j0 >> 13;                         // batch
    int n0 = j0 & 8191;                        // row within batch

    auto stageB1 = [&](int buf, int k0) {
#pragma unroll
        for (int qq = 0; qq < 4; ++qq) {
            int row = wv * 32 + qq * 8;
            async_cp16(&BS[buf * 16384 + row * 64],
                       W1b + (size_t)(row + lrow) * 384 + k0 + schunk * 8);
        }
    };
    auto loadF1 = [&](float* dst, int c0) {    // 64 rows c0..c0+64 -> dst[64][128] f32
        const float* src = feature1 + (size_t)bb * 1048576 + (size_t)c0 * 8192 + n0;
#pragma unroll
        for (int r = 0; r < 4; ++r) {          // 16 rows/round, 4 rounds
            int c = r * 16 + wv * 2;           // wave-uniform base row
            async_cp16(dst + (size_t)c * 128,
                       src + (size_t)(c + (lane >> 5)) * 8192 + (lane & 31) * 4);
        }
    };

    // ---- prefetch W1 tiles 0,1 + F1a BEFORE the NN scan (hidden under NN VALU) ----
    stageB1(0, 0);
    stageB1(1, 64);
    loadF1(F1a, 0);

    // ================= phase 0: three_nn for this block's 128 rows =================
    const float* p2 = pos2 + (size_t)bb * 6144;
    const float* p1 = pos1 + (size_t)bb * 24576;
    for (int i = tid; i < 2048; i += 512) {
        float x = p2[i], y = p2[2048 + i], z = p2[4096 + i];
        pk[i] = make_float4(x, y, z, -0.5f * (x * x + y * y + z * z));
    }
    __syncthreads();                           // drains prefetches too

    int p = lane & 15, ck = lane >> 4;
    int nq = n0 + wv * 16 + p;
    float qx = p1[nq], qy = p1[8192 + nq], qz = p1[16384 + nq];
    float ga0 = -3.4e38f, ga1 = -3.4e38f, ga2 = -3.4e38f;
    float gb0 = -3.4e38f, gb1 = -3.4e38f, gb2 = -3.4e38f;
    int ia0 = 0, ia1 = 0, ia2 = 0, ib0 = 0, ib1 = 0, ib2 = 0;
    int sbk = ck * 512, rot = 2 * ck;
    for (int h = 0; h < 8; ++h) {              // 8 sub-chunks of 64, no barriers
        int cb = sbk + h * 64;
        const float4* pc = pk + cb;
#pragma unroll 4
        for (int it = 0; it < 64; it += 2) {
            int i0 = (it + rot) & 63;          // per-group rotation: distinct banks
            float4 cdA = pc[i0];
            float4 cdB = pc[i0 + 1];
            {   // stream A
                int s = cb + i0;
                float tv = fmaf(qx, cdA.x, fmaf(qy, cdA.y, fmaf(qz, cdA.z, cdA.w)));
                bool c0 = tv > ga0, c1 = tv > ga1, c2 = tv > ga2;
                float o0 = ga0, o1 = ga1;
                ga2 = __builtin_amdgcn_fmed3f(tv, o1, ga2);
                ga1 = __builtin_amdgcn_fmed3f(tv, o0, o1);
                ga0 = fmaxf(o0, tv);
                ia2 = c1 ? ia1 : (c2 ? s : ia2);
                ia1 = c0 ? ia0 : (c1 ? s : ia1);
                ia0 = c0 ? s : ia0;
            }
            {   // stream B
                int s = cb + i0 + 1;
                float tv = fmaf(qx, cdB.x, fmaf(qy, cdB.y, fmaf(qz, cdB.z, cdB.w)));
                bool c0 = tv > gb0, c1 = tv > gb1, c2 = tv > gb2;
                float o0 = gb0, o1 = gb1;
                gb2 = __builtin_amdgcn_fmed3f(tv, o1, gb2);
                gb1 = __builtin_amdgcn_fmed3f(tv, o0, o1);
                gb0 = fmaxf(o0, tv);
                ib2 = c1 ? ib1 : (c2 ? s : ib2);
                ib1 = c0 ? ib0 : (c1 ? s : ib1);
                ib0 = c0 ? s : ib0;
            }
        }
    }
    u64 key0 = 0, key1 = 0, key2 = 0;
    ins3(((u64)fmono(ga0) << 32) | (u64)(2047 - ia0), key0, key1, key2);
    ins3(((u64)fmono(ga1) << 32) | (u64)(2047 - ia1), key0, key1, key2);
    ins3(((u64)fmono(ga2) << 32) | (u64)(2047 - ia2), key0, key1, key2);
    ins3(((u64)fmono(gb0) << 32) | (u64)(2047 - ib0), key0, key1, key2);
    ins3(((u64)fmono(gb1) << 32) | (u64)(2047 - ib1), key0, key1, key2);
    ins3(((u64)fmono(gb2) << 32) | (u64)(2047 - ib2), key0, key1, key2);
#pragma unroll
    for (int mask = 16; mask <= 32; mask <<= 1) {   // all lanes converge per p-class
        u64 m0 = shfl_xor_u64(key0, mask);
        u64 m1 = shfl_xor_u64(key1, mask);
        u64 m2 = shfl_xor_u64(key2, mask);
        ins3(m0, key0, key1, key2);
        ins3(m1, key0, key1, key2);
        ins3(m2, key0, key1, key2);
    }
    // ---- weights for this lane's query (all 64 lanes; pk reads, no global) ----
    int s0v = 2047 - (int)(key0 & 0xFFFFFFFFu);
    int s1v = 2047 - (int)(key1 & 0xFFFFFFFFu);
    int s2v = 2047 - (int)(key2 & 0xFFFFFFFFu);
    float w0n, w1n, w2n;
    {
        float n1 = qx * qx + qy * qy + qz * qz;
        float4 P0 = pk[s0v], P1 = pk[s1v], P2 = pk[s2v];
        float t0 = qx * P0.x + qy * P0.y + qz * P0.z + P0.w;
        float t1 = qx * P1.x + qy * P1.y + qz * P1.z + P1.w;
        float t2 = qx * P2.x + qy * P2.y + qz * P2.z + P2.w;
        float d0 = fmaxf(fmaf(-2.f, t0, n1), 1e-10f);
        float d1 = fmaxf(fmaf(-2.f, t1, n1), 1e-10f);
        float d2 = fmaxf(fmaf(-2.f, t2, n1), 1e-10f);
        float w0v = 1.f / d0, w1v = 1.f / d1, w2v = 1.f / d2;
        float inv = 1.f / (w0v + w1v + w2v);
        w0n = w0v * inv; w1n = w1v * inv; w2n = w2v * inv;
    }
    // ---- self-serve gather setup via shfl (rows wv*16+qq*8+lrow are OUR queries) ----
    const u16* gp0[2]; const u16* gp1[2]; const u16* gp2[2];
    float gw0[2], gw1[2], gw2[2];
    {
        const u16* fb = F2T + (size_t)bb * 2048 * 256;
#pragma unroll
        for (int qq = 0; qq < 2; ++qq) {
            int srcl = qq * 8 + lrow;          // lane holding query (row within wave)
            gp0[qq] = fb + (size_t)__shfl(s0v, srcl) * 256;
            gp1[qq] = fb + (size_t)__shfl(s1v, srcl) * 256;
            gp2[qq] = fb + (size_t)__shfl(s2v, srcl) * 256;
            gw0[qq] = __shfl(w0n, srcl);
            gw1[qq] = __shfl(w1n, srcl);
            gw2[qq] = __shfl(w2n, srcl);
        }
    }
    u16x8 G0[2], G1[2], G2[2];                 // in-flight gather registers
    auto gissue = [&](int k0) {
        int c = k0 + lchunk * 8;
#pragma unroll
        for (int qq = 0; qq < 2; ++qq) {
            G0[qq] = *(const u16x8*)(gp0[qq] + c);
            G1[qq] = *(const u16x8*)(gp1[qq] + c);
            G2[qq] = *(const u16x8*)(gp2[qq] + c);
        }
    };
    auto gwrite = [&](int buf) {
#pragma unroll
        for (int qq = 0; qq < 2; ++qq) {
            int row = wv * 16 + qq * 8;
            u16x8 o;
#pragma unroll
            for (int e = 0; e < 8; ++e)
                o[e] = f2b(gw0[qq] * b2f(G0[qq][e]) + gw1[qq] * b2f(G1[qq][e]) +
                           gw2[qq] * b2f(G2[qq][e]));
            *(u16x8*)&AS[buf * 8192 + (row + lrow) * 64 + schunk * 8] = o;
        }
    };
    auto buildF1 = [&](int buf, const float* F1) {   // AS tile from LDS f32 slab
#pragma unroll
        for (int qq = 0; qq < 2; ++qq) {
            int row = wv * 16 + qq * 8;
            u16x8 o;
#pragma unroll
            for (int w = 0; w < 8; ++w)
                o[w] = f2b(F1[(lchunk * 8 + w) * 128 + row + lrow]);
            *(u16x8*)&AS[buf * 8192 + (row + lrow) * 64 + schunk * 8] = o;
        }
    };
    auto stageB2 = [&](int buf, int k0) {
#pragma unroll
        for (int qq = 0; qq < 4; ++qq) {
            int row = wv * 32 + qq * 8;
            async_cp16(&BS2[buf * 16384 + row * 64],
                       W2b + (size_t)(row + lrow) * 256 + k0 + schunk * 8);
        }
    };

    gissue(0);
    __syncthreads();                           // pk reads done; also drains gissue
    loadF1(F1b, 64);                           // into pk's region (dead)
    gwrite(0);                                 // G regs already drained -> pure compute
    __syncthreads();

    f32x4 acc[2][8];
#pragma unroll
    for (int i = 0; i < 2; ++i)
#pragma unroll
        for (int jj = 0; jj < 8; ++jj) acc[i][jj] = (f32x4){0.f, 0.f, 0.f, 0.f};

    // ---------------- phase A: Y1 = A[128][384] x W1^T, pipelined ----------------
    for (int t = 0; t < 6; ++t) {
        int cur = t & 1;
        if (t < 3) gissue((t + 1) * 64);
        if (t >= 1 && t <= 4) stageB1((t + 1) & 1, (t + 1) * 64);
        if (t == 3) buildF1(0, F1a);
        if (t == 4) buildF1(1, F1b);
#pragma unroll
        for (int ks = 0; ks < 2; ++ks) {
            bf16x8 af[2];
#pragma unroll
            for (int i = 0; i < 2; ++i) {
                int row = wrow + i * 16 + l15;
                af[i] = *(const bf16x8*)&AS[cur * 8192 + row * 64 +
                                            ((ks * 4 + q) ^ (l15 & 7)) * 8];
            }
#pragma unroll
            for (int jj = 0; jj < 8; ++jj) {
                int brow = cbase + jj * 16 + l15;
                bf16x8 bfr = *(const bf16x8*)&BS[cur * 16384 + brow * 64 +
                                                 ((ks * 4 + q) ^ (l15 & 7)) * 8];
#pragma unroll
                for (int i = 0; i < 2; ++i)
                    acc[i][jj] = __builtin_amdgcn_mfma_f32_16x16x32_bf16(af[i], bfr,
                                                                         acc[i][jj], 0, 0, 0);
            }
        }
        if (t < 3) gwrite(cur ^ 1);            // gather latency covered by compute(t)
        __syncthreads();
    }

    // early W2 prefetch (BS2 buf0 region dead after the loop's last barrier)
    stageB2(0, 0);

    // ---- epilogue A: bias + per-channel stats ----
#pragma unroll
    for (int jj = 0; jj < 8; ++jj) {
        int c = cbase + jj * 16 + l15;
        float bv = b1[c];
        float s = 0.f, s2 = 0.f;
#pragma unroll
        for (int i = 0; i < 2; ++i)
#pragma unroll
            for (int r = 0; r < 4; ++r) {
                acc[i][jj][r] += bv;
                float v = acc[i][jj][r];
                s += v; s2 += v * v;
            }
        s += __shfl_xor(s, 16); s += __shfl_xor(s, 32);
        s2 += __shfl_xor(s2, 16); s2 += __shfl_xor(s2, 32);
        if (q == 0) { SC[rw * 256 + c] = s; SC2[rw * 256 + c] = s2; }
    }
    __syncthreads();
    if (tid < 256) {
        float fs = SC[tid] + SC[256 + tid] + SC[512 + tid] + SC[768 + tid];
        float fs2 = SC2[tid] + SC2[256 + tid] + SC2[512 + tid] + SC2[768 + tid];
        atomicAdd(&S1[sl + tid], (u64)(long long)llrintf(fs * FPSCALE));
        atomicAdd(&S1[sl + 256 + tid], (u64)(long long)llrintf(fs2 * FPSCALE));
    }
    gridbar(BAR, 256);

    // ---- BN1 fold ----
    if (tid < 256) {
        long long su = 0, sq = 0;
#pragma unroll
        for (int r = 0; r < NSLICE; ++r) {
            su += (long long)ld_agent_u64(&S1[r * 512 + tid]);
            sq += (long long)ld_agent_u64(&S1[r * 512 + 256 + tid]);
        }
        float fs = (float)su * FPINV;
        float fs2 = (float)sq * FPINV;
        const float inv = 1.f / 32768.f;
        float mean = fs * inv;
        float var = fs2 * inv - mean * mean;
        float a = g1[tid] * rsqrtf(var + 1e-5f);
        BNT[tid] = make_float2(a, be1[tid] - mean * a);
    }
    __syncthreads();

    // ---- build A2 tile in LDS: relu(bn1(bf16(Y1))), swizzled for MFMA reads ----
#pragma unroll
    for (int jj = 0; jj < 8; ++jj) {
        int c = cbase + jj * 16 + l15;
        float2 bn = BNT[c];
        int chunkbase = c >> 3;
        int win = c & 7;
#pragma unroll
        for (int i = 0; i < 2; ++i)
#pragma unroll
            for (int r = 0; r < 4; ++r) {
                int row = wrow + i * 16 + q * 4 + r;
                float vb = b2f(f2b(acc[i][jj][r]));       // bf16 round = Y1-store point
                u16 h = f2b(fmaxf(vb * bn.x + bn.y, 0.f));
                A2[row * 256 + ((chunkbase ^ (row & 7)) * 8 + win)] = h;
            }
    }
    __syncthreads();

    // ---------------- phase B: Y2 = A2[128][256] x W2^T, pipelined ----------------
#pragma unroll
    for (int i = 0; i < 2; ++i)
#pragma unroll
        for (int jj = 0; jj < 8; ++jj) acc[i][jj] = (f32x4){0.f, 0.f, 0.f, 0.f};

    for (int t = 0; t < 4; ++t) {
        int cur = t & 1;
        if (t < 3) stageB2(cur ^ 1, (t + 1) * 64);
#pragma unroll
        for (int ks = 0; ks < 2; ++ks) {
            bf16x8 af[2];
            int kc = t * 8 + ks * 4 + q;
#pragma unroll
            for (int i = 0; i < 2; ++i) {
                int row = wrow + i * 16 + l15;
                af[i] = *(const bf16x8*)&A2[row * 256 + ((kc ^ (l15 & 7)) * 8)];
            }
#pragma unroll
            for (int jj = 0; jj < 8; ++jj) {
                int brow = cbase + jj * 16 + l15;
                bf16x8 bfr = *(const bf16x8*)&BS2[cur * 16384 + brow * 64 +
                                                  ((ks * 4 + q) ^ (l15 & 7)) * 8];
#pragma unroll
                for (int i = 0; i < 2; ++i)
                    acc[i][jj] = __builtin_amdgcn_mfma_f32_16x16x32_bf16(af[i], bfr,
                                                                         acc[i][jj], 0, 0, 0);
            }
        }
        __syncthreads();
    }

    // ---- epilogue B: bias + stats ----
#pragma unroll
    for (int jj = 0; jj < 8; ++jj) {
        int c = cbase + jj * 16 + l15;
        float bv = b2[c];
        float s = 0.f, s2 = 0.f;
#pragma unroll
        for (int i = 0; i < 2; ++i)
#pragma unroll
            for (int r = 0; r < 4; ++r) {
                acc[i][jj][r] += bv;
                float v = acc[i][jj][r];
                s += v; s2 += v * v;
            }
        s += __shfl_xor(s, 16); s += __shfl_xor(s, 32);
        s2 += __shfl_xor(s2, 16); s2 += __shfl_xor(s2, 32);
        if (q == 0) { SC[rw * 256 + c] = s; SC2[rw * 256 + c] = s2; }
    }
    __syncthreads();
    if (tid < 256) {
        float fs = SC[tid] + SC[256 + tid] + SC[512 + tid] + SC[768 + tid];
        float fs2 = SC2[tid] + SC2[256 + tid] + SC2[512 + tid] + SC2[768 + tid];
        atomicAdd(&S2[sl + tid], (u64)(long long)llrintf(fs * FPSCALE));
        atomicAdd(&S2[sl + 256 + tid], (u64)(long long)llrintf(fs2 * FPSCALE));
    }
    gridbar(BAR, 512);

    // ---- BN2 fold ----
    if (tid < 256) {
        long long su = 0, sq = 0;
#pragma unroll
        for (int r = 0; r < NSLICE; ++r) {
            su += (long long)ld_agent_u64(&S2[r * 512 + tid]);
            sq += (long long)ld_agent_u64(&S2[r * 512 + 256 + tid]);
        }
        float fs = (float)su * FPINV;
        float fs2 = (float)sq * FPINV;
        const float inv = 1.f / 32768.f;
        float mean = fs * inv;
        float var = fs2 * inv - mean * mean;
        float a = g2[tid] * rsqrtf(var + 1e-5f);
        BNT[tid] = make_float2(a, be2[tid] - mean * a);
    }
    __syncthreads();

    // ---- store: out[b][o][n] = relu(bn2(bf16(Y2))) straight from registers ----
#pragma unroll
    for (int jj = 0; jj < 8; ++jj) {
        int o = cbase + jj * 16 + l15;
        float2 bn = BNT[o];
#pragma unroll
        for (int i = 0; i < 2; ++i) {
            int nn = n0 + wrow + i * 16 + q * 4;
            float4 v;
            v.x = fmaxf(b2f(f2b(acc[i][jj][0])) * bn.x + bn.y, 0.f);
            v.y = fmaxf(b2f(f2b(acc[i][jj][1])) * bn.x + bn.y, 0.f);
            v.z = fmaxf(b2f(f2b(acc[i][jj][2])) * bn.x + bn.y, 0.f);
            v.w = fmaxf(b2f(f2b(acc[i][jj][3])) * bn.x + bn.y, 0.f);
            *(float4*)&OUT[(size_t)bb * 2097152 + (size_t)o * 8192 + nn] = v;
        }
    }
}

extern "C" void kernel_launch(void* const* d_in, const int* in_sizes, int n_in,
                              void* d_out, int out_size, void* d_ws, size_t ws_size,
                              hipStream_t stream) {
    const float* pos1 = (const float*)d_in[0];
    const float* pos2 = (const float*)d_in[1];
    const float* feature1 = (const float*)d_in[2];
    const float* feature2 = (const float*)d_in[3];
    const float* W1 = (const float*)d_in[4];
    const float* b1 = (const float*)d_in[5];
    const float* g1 = (const float*)d_in[6];
    const float* be1 = (const float*)d_in[7];
    const float* W2 = (const float*)d_in[8];
    const float* b2 = (const float*)d_in[9];
    const float* g2 = (const float*)d_in[10];
    const float* be2 = (const float*)d_in[11];

    char* ws = (char*)d_ws;
    u16*    W1B   = (u16*)(ws + 786432);            // 196608 B
    u16*    W2B   = (u16*)(ws + 983040);            // 131072 B
    u16*    F2T   = (u16*)(ws + 1118208);           // 4 MiB  [4][2048][256]
    u64*    SSTAT = (u64*)(ws + 47255552);          // S1[16][512] | S2[16][512] | BAR
    u64*    S1    = SSTAT;
    u64*    S2    = SSTAT + NSLICE * 512;
    int*    BAR   = (int*)(SSTAT + 2 * NSLICE * 512);
    float*  OUT   = (float*)d_out;

    prep_kernel<<<NB_CVT + NB_T2 + 1, 256, 0, stream>>>(
        W1, W2, W1B, feature2, F2T, SSTAT);
    mlp_fused<<<256, 512, 0, stream>>>(pos1, pos2, F2T, feature1, W1B, b1, W2B, b2,
                                       S1, g1, be1, S2, g2, be2, OUT, BAR);
}

// Round 13
// 168.675 us; speedup vs baseline: 1.0337x; 1.0337x over previous
//
#include <hip/hip_runtime.h>
#include <hip/hip_bf16.h>
#include <cstdint>

typedef unsigned short u16;
typedef unsigned int u32;
typedef unsigned long long u64;
typedef __bf16 bf16x8 __attribute__((ext_vector_type(8)));
typedef float f32x4 __attribute__((ext_vector_type(4)));
typedef u16 u16x8 __attribute__((ext_vector_type(8)));

#define FPSCALE 1048576.0f          // 2^20 fixed-point for BN stats
#define FPINV   (1.0f / 1048576.0f)
#define NSLICE 16                   // atomic-contention slices

// ---------- helpers ----------
__device__ __forceinline__ u16 f2b(float f) {          // fp32 -> bf16 RNE
    unsigned int u = __float_as_uint(f);
    u += 0x7fffu + ((u >> 16) & 1u);
    return (u16)(u >> 16);
}
__device__ __forceinline__ float b2f(u16 h) {
    return __uint_as_float(((unsigned int)h) << 16);
}
__device__ __forceinline__ void async_cp16(void* lds, const void* g) {
    __builtin_amdgcn_global_load_lds((const __attribute__((address_space(1))) void*)g,
                                     (__attribute__((address_space(3))) void*)lds, 16, 0, 0);
}
__device__ __forceinline__ u64 ld_agent_u64(const u64* p) {
    return __hip_atomic_load(p, __ATOMIC_RELAXED, __HIP_MEMORY_SCOPE_AGENT);
}
// monotone unsigned mapping of float bits (order-preserving, EXACT)
__device__ __forceinline__ u32 fmono(float f) {
    u32 u = __float_as_uint(f);
    return u ^ (((u32)((int)u >> 31)) | 0x80000000u);
}
__device__ __forceinline__ u64 shfl_xor_u64(u64 v, int mask) {
    u32 lo = (u32)v, hi = (u32)(v >> 32);
    lo = (u32)__shfl_xor((int)lo, mask);
    hi = (u32)__shfl_xor((int)hi, mask);
    return ((u64)hi << 32) | lo;
}
// insert exact key into descending top-3 (keys unique: idx field breaks ties)
__device__ __forceinline__ void ins3(u64 k, u64& k0, u64& k1, u64& k2) {
    bool c0 = k > k0, c1 = k > k1, c2 = k > k2;
    k2 = c1 ? k1 : (c2 ? k : k2);
    k1 = c0 ? k0 : (c1 ? k : k1);
    k0 = c0 ? k : k0;
}
// padded pk index: one float4 pad every 64 entries
__device__ __forceinline__ int pkix(int i) { return i + (i >> 6); }

// ================= prep kernel: cvt + transposes + stat-zero ONLY =================
#define NB_CVT 160
#define NB_T2  512
#define NB_T1  1024

__global__ __launch_bounds__(256, 8) void prep_kernel(const float* __restrict__ w1,
                                                      const float* __restrict__ w2,
                                                      u16* __restrict__ wb,
                                                      const float* __restrict__ feature2,
                                                      u16* __restrict__ f2t,
                                                      const float* __restrict__ feature1,
                                                      u16* __restrict__ f1t,
                                                      u64* __restrict__ SZ) {
    __shared__ __align__(16) float t[64][65];
    int ci = blockIdx.x;
    int tid = threadIdx.x;

    if (ci >= NB_CVT + NB_T2 + NB_T1) {
        // ---- zero stats: S1[16][512] | S2[16][512] | BAR (per graph replay) ----
        for (int i = tid; i < 2 * NSLICE * 512; i += 256) SZ[i] = 0;
        if (tid == 0) *(int*)(SZ + 2 * NSLICE * 512) = 0;
        return;
    }
    if (ci < NB_CVT) {
        int i = ci * 256 + tid;
        if (i < 40960) {
            const float* src = (i < 24576) ? w1 : w2;
            int k = (i < 24576) ? i : (i - 24576);
            float4 v = *(const float4*)&src[(size_t)k * 4];
            ushort4 o;
            o.x = f2b(v.x); o.y = f2b(v.y); o.z = f2b(v.z); o.w = f2b(v.w);
            *(ushort4*)&wb[(size_t)i * 4] = o;
        }
        return;
    }
    // ---- transpose [B][C][S] -> [B][S][C] bf16 ----
    const float* in; u16* out; int C, S, s0, c0, b;
    if (ci < NB_CVT + NB_T2) {
        int lin = ci - NB_CVT;
        C = 256; S = 2048; in = feature2; out = f2t;
        s0 = (lin & 31) * 64; c0 = ((lin >> 5) & 3) * 64; b = lin >> 7;
    } else {
        int lin = ci - NB_CVT - NB_T2;
        C = 128; S = 8192; in = feature1; out = f1t;
        s0 = (lin & 127) * 64; c0 = ((lin >> 7) & 1) * 64; b = lin >> 8;
    }
    const float* ib = in + (size_t)b * C * S;
    u16* ob = out + (size_t)b * S * C;
    int col = tid & 63, r0 = tid >> 6;
#pragma unroll
    for (int p = 0; p < 16; ++p) {
        int c = p * 4 + r0;
        t[c][col] = ib[(size_t)(c0 + c) * S + s0 + col];
    }
    __syncthreads();
#pragma unroll
    for (int p = 0; p < 16; ++p) {
        int s = p * 4 + r0;
        ob[(size_t)(s0 + s) * C + c0 + col] = f2b(t[col][s]);
    }
}

// ================= mlp_fused: NN -> gather+GEMM1 -> BN1 -> GEMM2 -> BN2 -> out =================
// Phase-0 NN: wave-autonomous three_nn. 256 blocks x 8 waves = 2048 waves = one
// 16-query unit per wave (p=lane&15, ck=lane>>4 -> 512 cand/thread). Dual-stream top-3
// (even/odd chains); ids absolute (full 2048 staged once) -> ONE 6-key fold; merge via
// shfl_xor(16,32) only -- no cross-wave LDS, no barriers inside the scan. Results land
// in block-local LDS (IDXL/WGTL); this block's gather reads exactly those rows.
// R12 post-mortem (REVERTED): unpadded-pk rotation + buildF1 stride-512B reads were
// 8-way bank conflicts (1.1M events, +6us). Padded pk + IDXL handoff restored.
__device__ __forceinline__ void gridbar(int* cnt, int target) {
    __syncthreads();                 // drain this block's stat atomics (vmcnt 0)
    if (threadIdx.x == 0) {
        __hip_atomic_fetch_add(cnt, 1, __ATOMIC_RELAXED, __HIP_MEMORY_SCOPE_AGENT);
        while (__hip_atomic_load(cnt, __ATOMIC_RELAXED, __HIP_MEMORY_SCOPE_AGENT) < target)
            __builtin_amdgcn_s_sleep(16);
        __atomic_signal_fence(__ATOMIC_SEQ_CST);   // compiler barrier only
    }
    __syncthreads();
}

__global__ __launch_bounds__(512, 1) void mlp_fused(const float* __restrict__ pos1,
                                                    const float* __restrict__ pos2,
                                                    const u16* __restrict__ F2T,
                                                    const u16* __restrict__ A2g,  // F1T
                                                    const u16* __restrict__ W1b,
                                                    const float* __restrict__ b1,
                                                    const u16* __restrict__ W2b,
                                                    const float* __restrict__ b2,
                                                    u64* __restrict__ S1,
                                                    const float* __restrict__ g1,
                                                    const float* __restrict__ be1,
                                                    u64* __restrict__ S2,
                                                    const float* __restrict__ g2,
                                                    const float* __restrict__ be2,
                                                    float* __restrict__ OUT,
                                                    int* __restrict__ BAR) {
    __shared__ __align__(16) char smem[141312];
    u16* AS  = (u16*)smem;                     // phase A: A dbuf 2x[128][64] (32 KB)
    u16* BS  = (u16*)(smem + 32768);           // phase A: B dbuf 2x[256][64] (64 KB)
    u16* A2  = (u16*)smem;                     // phase B: A tile [128][256]  (64 KB, overlay)
    u16* BS2 = (u16*)(smem + 65536);           // phase B: B dbuf 2x[256][64] (64 KB)
    float* SC  = (float*)(smem + 131072);      // stats scratch [4][256] (4 KB)
    float* SC2 = (float*)(smem + 135168);      // 4 KB
    float2* BNT = (float2*)(smem + 139264);    // 2 KB fold table
    // NN-phase overlays (dead before GEMM staging):
    float4* pk  = (float4*)smem;               // padded 2080 float4 = 33280 B
    int*   IDXL = (int*)(smem + 33280);        // [128][3]  (1536 B)
    float* WGTL = (float*)(smem + 34816);      // [128][3]  (1536 B)

    int tid = threadIdx.x, bid = blockIdx.x;
    int lane = tid & 63, wv = tid >> 6;        // 8 waves
    int l15 = lane & 15, q = lane >> 4;
    int lrow = lane >> 3, lchunk = lane & 7, schunk = lchunk ^ lrow;
    int j0 = bid * 128;
    int rw = wv & 3;                           // row-group (4)
    int cg = wv >> 2;                          // col-group (2)
    int wrow = rw * 32;
    int cbase = cg * 128;
    int sl = (bid & (NSLICE - 1)) * 512;
    int bb = j0 >> 13;                         // batch

    // ================= phase 0: three_nn for this block's 128 rows =================
    {
        const float* p2 = pos2 + (size_t)bb * 6144;
        const float* p1 = pos1 + (size_t)bb * 24576;
        for (int i = tid; i < 2048; i += 512) {
            float x = p2[i], y = p2[2048 + i], z = p2[4096 + i];
            pk[pkix(i)] = make_float4(x, y, z, -0.5f * (x * x + y * y + z * z));
        }
        __syncthreads();

        int p = lane & 15, ck = lane >> 4;
        int nq = (j0 & 8191) + wv * 16 + p;
        float qx = p1[nq], qy = p1[8192 + nq], qz = p1[16384 + nq];
        float ga0 = -3.4e38f, ga1 = -3.4e38f, ga2 = -3.4e38f;
        float gb0 = -3.4e38f, gb1 = -3.4e38f, gb2 = -3.4e38f;
        int ia0 = 0, ia1 = 0, ia2 = 0, ib0 = 0, ib1 = 0, ib2 = 0;
        int sb = ck * 512;
        for (int h = 0; h < 8; ++h) {          // 8 sub-chunks of 64, no barriers
            int cb = sb + h * 64;
            const float4* pc = pk + pkix(cb);  // pad-safe: cb%64==0
#pragma unroll 4
            for (int it = 0; it < 64; it += 2) {
                float4 cdA = pc[it];
                float4 cdB = pc[it + 1];
                {   // stream A
                    int s = cb + it;
                    float tv = fmaf(qx, cdA.x, fmaf(qy, cdA.y, fmaf(qz, cdA.z, cdA.w)));
                    bool c0 = tv > ga0, c1 = tv > ga1, c2 = tv > ga2;
                    float o0 = ga0, o1 = ga1;
                    ga2 = __builtin_amdgcn_fmed3f(tv, o1, ga2);
                    ga1 = __builtin_amdgcn_fmed3f(tv, o0, o1);
                    ga0 = fmaxf(o0, tv);
                    ia2 = c1 ? ia1 : (c2 ? s : ia2);
                    ia1 = c0 ? ia0 : (c1 ? s : ia1);
                    ia0 = c0 ? s : ia0;
                }
                {   // stream B
                    int s = cb + it + 1;
                    float tv = fmaf(qx, cdB.x, fmaf(qy, cdB.y, fmaf(qz, cdB.z, cdB.w)));
                    bool c0 = tv > gb0, c1 = tv > gb1, c2 = tv > gb2;
                    float o0 = gb0, o1 = gb1;
                    gb2 = __builtin_amdgcn_fmed3f(tv, o1, gb2);
                    gb1 = __builtin_amdgcn_fmed3f(tv, o0, o1);
                    gb0 = fmaxf(o0, tv);
                    ib2 = c1 ? ib1 : (c2 ? s : ib2);
                    ib1 = c0 ? ib0 : (c1 ? s : ib1);
                    ib0 = c0 ? s : ib0;
                }
            }
        }
        u64 key0 = 0, key1 = 0, key2 = 0;
        ins3(((u64)fmono(ga0) << 32) | (u64)(2047 - ia0), key0, key1, key2);
        ins3(((u64)fmono(ga1) << 32) | (u64)(2047 - ia1), key0, key1, key2);
        ins3(((u64)fmono(ga2) << 32) | (u64)(2047 - ia2), key0, key1, key2);
        ins3(((u64)fmono(gb0) << 32) | (u64)(2047 - ib0), key0, key1, key2);
        ins3(((u64)fmono(gb1) << 32) | (u64)(2047 - ib1), key0, key1, key2);
        ins3(((u64)fmono(gb2) << 32) | (u64)(2047 - ib2), key0, key1, key2);
        // merge the 4 chunk-groups (lanes p, p+16, p+32, p+48) -- in-wave only
#pragma unroll
        for (int mask = 16; mask <= 32; mask <<= 1) {
            u64 m0 = shfl_xor_u64(key0, mask);
            u64 m1 = shfl_xor_u64(key1, mask);
            u64 m2 = shfl_xor_u64(key2, mask);
            ins3(m0, key0, key1, key2);
            ins3(m1, key0, key1, key2);
            ins3(m2, key0, key1, key2);
        }
        if (lane < 16) {
            int s0 = 2047 - (int)(key0 & 0xFFFFFFFFu);
            int s1 = 2047 - (int)(key1 & 0xFFFFFFFFu);
            int s2 = 2047 - (int)(key2 & 0xFFFFFFFFu);
            int r = wv * 16 + p;               // row within block
            int nn = (j0 & 8191) + r;
            float x1 = p1[nn], y1 = p1[8192 + nn], z1 = p1[16384 + nn];
            float n1 = x1 * x1 + y1 * y1 + z1 * z1;
            float X0 = p2[s0], Y0 = p2[2048 + s0], Z0 = p2[4096 + s0];
            float X1 = p2[s1], Y1v = p2[2048 + s1], Z1 = p2[4096 + s1];
            float X2 = p2[s2], Y2v = p2[2048 + s2], Z2 = p2[4096 + s2];
            float t0 = x1 * X0 + y1 * Y0 + z1 * Z0 - 0.5f * (X0 * X0 + Y0 * Y0 + Z0 * Z0);
            float t1 = x1 * X1 + y1 * Y1v + z1 * Z1 - 0.5f * (X1 * X1 + Y1v * Y1v + Z1 * Z1);
            float t2 = x1 * X2 + y1 * Y2v + z1 * Z2 - 0.5f * (X2 * X2 + Y2v * Y2v + Z2 * Z2);
            float d0 = fmaxf(fmaf(-2.f, t0, n1), 1e-10f);
            float d1 = fmaxf(fmaf(-2.f, t1, n1), 1e-10f);
            float d2 = fmaxf(fmaf(-2.f, t2, n1), 1e-10f);
            float w0v = 1.f / d0, w1v = 1.f / d1, w2v = 1.f / d2;
            float inv = 1.f / (w0v + w1v + w2v);
            IDXL[r * 3 + 0] = s0; IDXL[r * 3 + 1] = s1; IDXL[r * 3 + 2] = s2;
            WGTL[r * 3 + 0] = w0v * inv; WGTL[r * 3 + 1] = w1v * inv; WGTL[r * 3 + 2] = w2v * inv;
        }
    }
    __syncthreads();

    // gather row pointers + weights for this thread's 2 staging rows (from LDS)
    const u16* gp0[2]; const u16* gp1[2]; const u16* gp2[2];
    float gw0[2], gw1[2], gw2[2];
    {
        const u16* fb = F2T + (size_t)bb * 2048 * 256;
#pragma unroll
        for (int qq = 0; qq < 2; ++qq) {
            int r = wv * 16 + qq * 8 + lrow;
            gp0[qq] = fb + (size_t)IDXL[r * 3 + 0] * 256;
            gp1[qq] = fb + (size_t)IDXL[r * 3 + 1] * 256;
            gp2[qq] = fb + (size_t)IDXL[r * 3 + 2] * 256;
            gw0[qq] = WGTL[r * 3 + 0]; gw1[qq] = WGTL[r * 3 + 1]; gw2[qq] = WGTL[r * 3 + 2];
        }
    }
    __syncthreads();   // idxw consumed by ALL waves before staging clobbers it

    u16x8 G0[2], G1[2], G2[2];                 // in-flight gather registers

    f32x4 acc[2][8];
#pragma unroll
    for (int i = 0; i < 2; ++i)
#pragma unroll
        for (int jj = 0; jj < 8; ++jj) acc[i][jj] = (f32x4){0.f, 0.f, 0.f, 0.f};

    auto stageB1 = [&](int buf, int k0) {
#pragma unroll
        for (int qq = 0; qq < 4; ++qq) {
            int row = wv * 32 + qq * 8;
            async_cp16(&BS[buf * 16384 + row * 64],
                       W1b + (size_t)(row + lrow) * 384 + k0 + schunk * 8);
        }
    };
    auto stageA1f1 = [&](int buf, int k0) {    // k>=256: dense from F1T (async)
        const u16* src = A2g + (size_t)j0 * 128 + (k0 - 256);
#pragma unroll
        for (int qq = 0; qq < 2; ++qq) {
            int row = wv * 16 + qq * 8;
            async_cp16(&AS[buf * 8192 + row * 64],
                       src + (size_t)(row + lrow) * 128 + schunk * 8);
        }
    };
    auto gissue = [&](int k0) {                // issue gather loads (no wait)
        int c = k0 + lchunk * 8;
#pragma unroll
        for (int qq = 0; qq < 2; ++qq) {
            G0[qq] = *(const u16x8*)(gp0[qq] + c);
            G1[qq] = *(const u16x8*)(gp1[qq] + c);
            G2[qq] = *(const u16x8*)(gp2[qq] + c);
        }
    };
    auto gwrite = [&](int buf) {               // combine + swizzled ds_write
#pragma unroll
        for (int qq = 0; qq < 2; ++qq) {
            int row = wv * 16 + qq * 8;
            u16x8 o;
#pragma unroll
            for (int e = 0; e < 8; ++e)
                o[e] = f2b(gw0[qq] * b2f(G0[qq][e]) + gw1[qq] * b2f(G1[qq][e]) +
                           gw2[qq] * b2f(G2[qq][e]));
            *(u16x8*)&AS[buf * 8192 + (row + lrow) * 64 + schunk * 8] = o;
        }
    };
    auto stageB2 = [&](int buf, int k0) {
#pragma unroll
        for (int qq = 0; qq < 4; ++qq) {
            int row = wv * 32 + qq * 8;
            async_cp16(&BS2[buf * 16384 + row * 64],
                       W2b + (size_t)(row + lrow) * 256 + k0 + schunk * 8);
        }
    };

    // ---------------- phase A: Y1 = A[128][384] x W1^T, pipelined ----------------
    gissue(0);
    stageB1(0, 0);
    gwrite(0);                                  // prologue: wait is unavoidable here
    __syncthreads();
    for (int t = 0; t < 6; ++t) {
        int cur = t & 1;
        if (t < 3) { gissue((t + 1) * 64); stageB1(cur ^ 1, (t + 1) * 64); }
        else if (t < 5) { stageB1(cur ^ 1, (t + 1) * 64); stageA1f1(cur ^ 1, (t + 1) * 64); }
#pragma unroll
        for (int ks = 0; ks < 2; ++ks) {
            bf16x8 af[2];
#pragma unroll
            for (int i = 0; i < 2; ++i) {
                int row = wrow + i * 16 + l15;
                af[i] = *(const bf16x8*)&AS[cur * 8192 + row * 64 +
                                            ((ks * 4 + q) ^ (l15 & 7)) * 8];
            }
#pragma unroll
            for (int jj = 0; jj < 8; ++jj) {
                int brow = cbase + jj * 16 + l15;
                bf16x8 bfr = *(const bf16x8*)&BS[cur * 16384 + brow * 64 +
                                                 ((ks * 4 + q) ^ (l15 & 7)) * 8];
#pragma unroll
                for (int i = 0; i < 2; ++i)
                    acc[i][jj] = __builtin_amdgcn_mfma_f32_16x16x32_bf16(af[i], bfr,
                                                                         acc[i][jj], 0, 0, 0);
            }
        }
        if (t < 3) gwrite(cur ^ 1);             // gather latency covered by compute(t)
        __syncthreads();
    }

    // early W2 prefetch (BS2 buf0 region dead after the loop's last barrier)
    stageB2(0, 0);

    // ---- epilogue A: bias + per-channel stats ----
#pragma unroll
    for (int jj = 0; jj < 8; ++jj) {
        int c = cbase + jj * 16 + l15;
        float bv = b1[c];
        float s = 0.f, s2 = 0.f;
#pragma unroll
        for (int i = 0; i < 2; ++i)
#pragma unroll
            for (int r = 0; r < 4; ++r) {
                acc[i][jj][r] += bv;
                float v = acc[i][jj][r];
                s += v; s2 += v * v;
            }
        s += __shfl_xor(s, 16); s += __shfl_xor(s, 32);
        s2 += __shfl_xor(s2, 16); s2 += __shfl_xor(s2, 32);
        if (q == 0) { SC[rw * 256 + c] = s; SC2[rw * 256 + c] = s2; }
    }
    __syncthreads();
    if (tid < 256) {
        float fs = SC[tid] + SC[256 + tid] + SC[512 + tid] + SC[768 + tid];
        float fs2 = SC2[tid] + SC2[256 + tid] + SC2[512 + tid] + SC2[768 + tid];
        atomicAdd(&S1[sl + tid], (u64)(long long)llrintf(fs * FPSCALE));
        atomicAdd(&S1[sl + 256 + tid], (u64)(long long)llrintf(fs2 * FPSCALE));
    }
    gridbar(BAR, 256);

    // ---- BN1 fold ----
    if (tid < 256) {
        long long su = 0, sq = 0;
#pragma unroll
        for (int r = 0; r < NSLICE; ++r) {
            su += (long long)ld_agent_u64(&S1[r * 512 + tid]);
            sq += (long long)ld_agent_u64(&S1[r * 512 + 256 + tid]);
        }
        float fs = (float)su * FPINV;
        float fs2 = (float)sq * FPINV;
        const float inv = 1.f / 32768.f;
        float mean = fs * inv;
        float var = fs2 * inv - mean * mean;
        float a = g1[tid] * rsqrtf(var + 1e-5f);
        BNT[tid] = make_float2(a, be1[tid] - mean * a);
    }
    __syncthreads();

    // ---- build A2 tile in LDS: relu(bn1(bf16(Y1))), swizzled for MFMA reads ----
#pragma unroll
    for (int jj = 0; jj < 8; ++jj) {
        int c = cbase + jj * 16 + l15;
        float2 bn = BNT[c];
        int chunkbase = c >> 3;
        int win = c & 7;
#pragma unroll
        for (int i = 0; i < 2; ++i)
#pragma unroll
            for (int r = 0; r < 4; ++r) {
                int row = wrow + i * 16 + q * 4 + r;
                float vb = b2f(f2b(acc[i][jj][r]));       // bf16 round = Y1-store point
                u16 h = f2b(fmaxf(vb * bn.x + bn.y, 0.f));
                A2[row * 256 + ((chunkbase ^ (row & 7)) * 8 + win)] = h;
            }
    }
    __syncthreads();

    // ---------------- phase B: Y2 = A2[128][256] x W2^T, pipelined ----------------
#pragma unroll
    for (int i = 0; i < 2; ++i)
#pragma unroll
        for (int jj = 0; jj < 8; ++jj) acc[i][jj] = (f32x4){0.f, 0.f, 0.f, 0.f};

    for (int t = 0; t < 4; ++t) {
        int cur = t & 1;
        if (t < 3) stageB2(cur ^ 1, (t + 1) * 64);
#pragma unroll
        for (int ks = 0; ks < 2; ++ks) {
            bf16x8 af[2];
            int kc = t * 8 + ks * 4 + q;
#pragma unroll
            for (int i = 0; i < 2; ++i) {
                int row = wrow + i * 16 + l15;
                af[i] = *(const bf16x8*)&A2[row * 256 + ((kc ^ (l15 & 7)) * 8)];
            }
#pragma unroll
            for (int jj = 0; jj < 8; ++jj) {
                int brow = cbase + jj * 16 + l15;
                bf16x8 bfr = *(const bf16x8*)&BS2[cur * 16384 + brow * 64 +
                                                  ((ks * 4 + q) ^ (l15 & 7)) * 8];
#pragma unroll
                for (int i = 0; i < 2; ++i)
                    acc[i][jj] = __builtin_amdgcn_mfma_f32_16x16x32_bf16(af[i], bfr,
                                                                         acc[i][jj], 0, 0, 0);
            }
        }
        __syncthreads();
    }

    // ---- epilogue B: bias + stats ----
#pragma unroll
    for (int jj = 0; jj < 8; ++jj) {
        int c = cbase + jj * 16 + l15;
        float bv = b2[c];
        float s = 0.f, s2 = 0.f;
#pragma unroll
        for (int i = 0; i < 2; ++i)
#pragma unroll
            for (int r = 0; r < 4; ++r) {
                acc[i][jj][r] += bv;
                float v = acc[i][jj][r];
                s += v; s2 += v * v;
            }
        s += __shfl_xor(s, 16); s += __shfl_xor(s, 32);
        s2 += __shfl_xor(s2, 16); s2 += __shfl_xor(s2, 32);
        if (q == 0) { SC[rw * 256 + c] = s; SC2[rw * 256 + c] = s2; }
    }
    __syncthreads();
    if (tid < 256) {
        float fs = SC[tid] + SC[256 + tid] + SC[512 + tid] + SC[768 + tid];
        float fs2 = SC2[tid] + SC2[256 + tid] + SC2[512 + tid] + SC2[768 + tid];
        atomicAdd(&S2[sl + tid], (u64)(long long)llrintf(fs * FPSCALE));
        atomicAdd(&S2[sl + 256 + tid], (u64)(long long)llrintf(fs2 * FPSCALE));
    }
    gridbar(BAR, 512);

    // ---- BN2 fold ----
    if (tid < 256) {
        long long su = 0, sq = 0;
#pragma unroll
        for (int r = 0; r < NSLICE; ++r) {
            su += (long long)ld_agent_u64(&S2[r * 512 + tid]);
            sq += (long long)ld_agent_u64(&S2[r * 512 + 256 + tid]);
        }
        float fs = (float)su * FPINV;
        float fs2 = (float)sq * FPINV;
        const float inv = 1.f / 32768.f;
        float mean = fs * inv;
        float var = fs2 * inv - mean * mean;
        float a = g2[tid] * rsqrtf(var + 1e-5f);
        BNT[tid] = make_float2(a, be2[tid] - mean * a);
    }
    __syncthreads();

    // ---- store: out[b][o][n] = relu(bn2(bf16(Y2))) straight from registers ----
    int nbase = j0 & 8191;
#pragma unroll
    for (int jj = 0; jj < 8; ++jj) {
        int o = cbase + jj * 16 + l15;
        float2 bn = BNT[o];
#pragma unroll
        for (int i = 0; i < 2; ++i) {
            int n0 = nbase + wrow + i * 16 + q * 4;
            float4 v;
            v.x = fmaxf(b2f(f2b(acc[i][jj][0])) * bn.x + bn.y, 0.f);
            v.y = fmaxf(b2f(f2b(acc[i][jj][1])) * bn.x + bn.y, 0.f);
            v.z = fmaxf(b2f(f2b(acc[i][jj][2])) * bn.x + bn.y, 0.f);
            v.w = fmaxf(b2f(f2b(acc[i][jj][3])) * bn.x + bn.y, 0.f);
            *(float4*)&OUT[(size_t)bb * 2097152 + (size_t)o * 8192 + n0] = v;
        }
    }
}

extern "C" void kernel_launch(void* const* d_in, const int* in_sizes, int n_in,
                              void* d_out, int out_size, void* d_ws, size_t ws_size,
                              hipStream_t stream) {
    const float* pos1 = (const float*)d_in[0];
    const float* pos2 = (const float*)d_in[1];
    const float* feature1 = (const float*)d_in[2];
    const float* feature2 = (const float*)d_in[3];
    const float* W1 = (const float*)d_in[4];
    const float* b1 = (const float*)d_in[5];
    const float* g1 = (const float*)d_in[6];
    const float* be1 = (const float*)d_in[7];
    const float* W2 = (const float*)d_in[8];
    const float* b2 = (const float*)d_in[9];
    const float* g2 = (const float*)d_in[10];
    const float* be2 = (const float*)d_in[11];

    char* ws = (char*)d_ws;
    u16*    W1B   = (u16*)(ws + 786432);            // 196608 B
    u16*    W2B   = (u16*)(ws + 983040);            // 131072 B
    u16*    F2T   = (u16*)(ws + 1118208);           // 4 MiB  [4][2048][256]
    u16*    F1T   = (u16*)(ws + 5312512);           // 8 MiB  [4][8192][128]
    u64*    SSTAT = (u64*)(ws + 47255552);          // S1[16][512] | S2[16][512] | BAR
    u64*    S1    = SSTAT;
    u64*    S2    = SSTAT + NSLICE * 512;
    int*    BAR   = (int*)(SSTAT + 2 * NSLICE * 512);
    float*  OUT   = (float*)d_out;

    prep_kernel<<<NB_CVT + NB_T2 + NB_T1 + 1, 256, 0, stream>>>(
        W1, W2, W1B, feature2, F2T, feature1, F1T, SSTAT);
    mlp_fused<<<256, 512, 0, stream>>>(pos1, pos2, F2T, F1T, W1B, b1, W2B, b2,
                                       S1, g1, be1, S2, g2, be2, OUT, BAR);
}